// Round 13
// baseline (325.846 us; speedup 1.0000x reference)
//
#include <hip/hip_runtime.h>
#include <stdint.h>

// Problem constants
#define T_TOK 4096
#define H_DIM 4096
#define I_DIM 1408
#define E_NUM 16
#define TPE   256

typedef __attribute__((ext_vector_type(4))) int   i32x4;
typedef __attribute__((ext_vector_type(2))) int   i32x2;
typedef __attribute__((ext_vector_type(4))) float f32x4;

// counted waits (T4): vmcnt never drains to 0 in the steady-state loop.
#define VMCNT(n) asm volatile("s_waitcnt vmcnt(" #n ")" ::: "memory")
#define LGKM0()  asm volatile("s_waitcnt lgkmcnt(0)" ::: "memory")

// async global->LDS, 16B/lane. LDS dest is WAVE-UNIFORM base; HW writes
// base + lane*16. Global src is per-lane (so we pre-swizzle the source).
__device__ __forceinline__ void gload16(const void* g, void* l) {
  __builtin_amdgcn_global_load_lds(
      (const __attribute__((address_space(1))) void*)g,
      (__attribute__((address_space(3))) void*)l, 16, 0, 0);
}

// swizzle key: involution on the 4 16B-blocks of a 64B LDS row.
__device__ __forceinline__ int fswz(int r) { return (r ^ (r >> 2)) & 3; }

// ---------------------------------------------------------------------------
// Kernel 1: dynamic per-token quant of x (f32 -> int8 + scale). 1 block/token.
// ---------------------------------------------------------------------------
__global__ __launch_bounds__(256)
void quant_x_kernel(const float* __restrict__ x,
                    int8_t* __restrict__ xq,
                    float* __restrict__ s1) {
  const int t   = blockIdx.x;
  const int tid = threadIdx.x;
  const float* row = x + (size_t)t * H_DIM;

  f32x4 v[4];
  float mx = 0.0f;
#pragma unroll
  for (int i = 0; i < 4; ++i) {
    v[i] = *(const f32x4*)(row + (size_t)(i * 256 + tid) * 4);
#pragma unroll
    for (int j = 0; j < 4; ++j) mx = fmaxf(mx, fabsf(v[i][j]));
  }
#pragma unroll
  for (int off = 32; off > 0; off >>= 1) mx = fmaxf(mx, __shfl_xor(mx, off));
  __shared__ float wmax[4];
  if ((tid & 63) == 0) wmax[tid >> 6] = mx;
  __syncthreads();
  float s = fmaxf(fmaxf(wmax[0], wmax[1]), fmaxf(wmax[2], wmax[3])) / 127.0f;
  s = fmaxf(s, 1e-30f);

  int* orow = (int*)(xq + (size_t)t * H_DIM);
#pragma unroll
  for (int i = 0; i < 4; ++i) {
    int packed = 0;
#pragma unroll
    for (int j = 0; j < 4; ++j) {
      float q = rintf(v[i][j] / s);              // rintf = half-even = jnp.round
      q = fminf(fmaxf(q, -128.0f), 127.0f);
      packed |= ((int)q & 0xff) << (8 * j);
    }
    orow[i * 256 + tid] = packed;
  }
  if (tid == 0) s1[t] = s;
}

// ---------------------------------------------------------------------------
// Kernel 3: h = silu(gate)*up*smooth; per-token quant -> hq, s2. 1 block/token.
// ---------------------------------------------------------------------------
__global__ __launch_bounds__(256)
void act_quant_kernel(const float* __restrict__ y,
                      const float* __restrict__ smooth,
                      int8_t* __restrict__ hq,
                      float* __restrict__ s2) {
  const int t   = blockIdx.x;
  const int e   = t >> 8;               // TPE = 256
  const int tid = threadIdx.x;
  const float* gate = y + (size_t)t * (2 * I_DIM);
  const float* up   = gate + I_DIM;
  const float* ss   = smooth + (size_t)e * I_DIM;
  constexpr int NV = I_DIM / 4;          // 352 vec4 per row

  f32x4 h[2];
  float mx = 0.0f;
#pragma unroll
  for (int i = 0; i < 2; ++i) {
    const int idx = tid + i * 256;
    h[i] = (f32x4)(0.0f);
    if (idx < NV) {
      const f32x4 g4 = *(const f32x4*)(gate + idx * 4);
      const f32x4 u4 = *(const f32x4*)(up + idx * 4);
      const f32x4 s4 = *(const f32x4*)(ss + idx * 4);
#pragma unroll
      for (int j = 0; j < 4; ++j) {
        const float g = g4[j];
        const float sig = 1.0f / (1.0f + expf(-g));
        h[i][j] = ((g * sig) * u4[j]) * s4[j];
        mx = fmaxf(mx, fabsf(h[i][j]));
      }
    }
  }
#pragma unroll
  for (int off = 32; off > 0; off >>= 1) mx = fmaxf(mx, __shfl_xor(mx, off));
  __shared__ float wmax[4];
  if ((tid & 63) == 0) wmax[tid >> 6] = mx;
  __syncthreads();
  float s = fmaxf(fmaxf(wmax[0], wmax[1]), fmaxf(wmax[2], wmax[3])) / 127.0f;
  s = fmaxf(s, 1e-30f);

  int* orow = (int*)(hq + (size_t)t * I_DIM);   // 1408 % 16 == 0, aligned
#pragma unroll
  for (int i = 0; i < 2; ++i) {
    const int idx = tid + i * 256;
    if (idx < NV) {
      int packed = 0;
#pragma unroll
      for (int j = 0; j < 4; ++j) {
        float q = rintf(h[i][j] / s);
        q = fminf(fmaxf(q, -128.0f), 127.0f);
        packed |= ((int)q & 0xff) << (8 * j);
      }
      orow[idx] = packed;
    }
  }
  if (tid == 0) s2[t] = s;
}

// ---------------------------------------------------------------------------
// Grouped int8 GEMM, weights arrive as INT32 (truncated to int8 on the fly).
//   A: (E*TPE, K) int8; B32: (E, N, K) int32; C = ((f32)acc*sN[e,n])*sM[t]
// Tile M=256 (whole expert: weights read once) x N=64, BK=64 (1 MFMA k-step).
// 512 thr = 8 waves (4M x 2N); wave = 64x32 = 4x2 mfma_i32_16x16x64_i8 frags.
//
// LDS 40 KB + __launch_bounds__(512,6) -> 3 blocks/CU co-resident:
// smooths per-block barrier windows against the HBM stream and makes gemm1's
// whole 704-block grid co-resident (zero tail round).
//
// Counted-vmcnt schedule (one s_barrier/iter; vmcnt floor = 2; wave-UNIFORM
// staging so the counts hold for every wave):
//   iter t (entering: As/Bs[t&1] valid; outstanding = B(t+1) regs x2):
//     1. issue A(t+1) x2 gload16            (outstanding: B(t+1)2 + A(t+1)2)
//     2. ds_read + 8 MFMA on tile t
//     3. VMCNT(2) -> B(t+1) regs arrived
//     4. pack -> ds_write_b64 Bs[(t+1)&1]
//     5. issue B(t+2) x2                    (outstanding: A(t+1)2 + B(t+2)2)
//     6. VMCNT(2) -> A(t+1) done; B(t+2) stays in flight ACROSS the barrier
//     7. LGKM0 + s_barrier
// XCD-pinned expert mapping: rid&7 = XCD owns 2 experts (A stays L2-hot).
// Swizzle (both sides, involution): LDS(row,16B-blk)=global(row,blk^fswz(row)).
// ---------------------------------------------------------------------------
template <int N, int K, int NBLK>   // NBLK = N/64
__global__ __launch_bounds__(512, 6)
void gemm_i8_w32_kernel(const int8_t* __restrict__ A,
                        const int* __restrict__ B32,
                        float* __restrict__ C,
                        const float* __restrict__ scaleN,
                        const float* __restrict__ scaleM) {
  constexpr int NT = K / 64;
  __shared__ __align__(16) int8_t As[2][256 * 64];   // 16 KB each
  __shared__ __align__(16) int8_t Bs[2][64 * 64];    //  4 KB each

  // --- XCD-pinned (expert, n-tile) mapping ---
  const int rid  = blockIdx.x;
  const int xcd  = rid & 7;
  const int slot = rid >> 3;
  const int el   = (slot >= NBLK) ? 1 : 0;
  const int e    = 2 * xcd + el;
  const int bn   = slot - el * NBLK;

  const int tid  = threadIdx.x;
  const int lane = tid & 63;
  const int wid  = tid >> 6;          // 0..7
  const int wm   = wid >> 1;          // 0..3  (64-row quadrant of 256)
  const int wn   = wid & 1;           // 0..1  (32-col half of 64)

  const int8_t* Abase = A + (size_t)e * TPE * K;
  const int*    Bbase = B32 + ((size_t)e * N + (size_t)bn * 64) * (size_t)K;

  // --- A staging: 2 chunks/thread (rows tid>>2 and 128+(tid>>2)) ---
  const int arow = tid >> 2;                   // 0..127
  const int ablk = tid & 3;
  const int agblk = ablk ^ fswz(arow);         // fswz(arow+128)==fswz(arow)
  const int8_t* gA0 = Abase + (size_t)arow * K + (agblk << 4);
  const int8_t* gA1 = gA0 + (size_t)128 * K;

  // --- B staging (uniform, all 512 threads): 8 ints -> 8 int8 (b64 write) ---
  const int brow  = tid >> 3;                  // 0..63
  const int bcol8 = tid & 7;                   // which 8-int8 granule
  const int* gB = Bbase + (size_t)brow * K + bcol8 * 8;    // int units
  const int bldsOff = brow * 64 + (((bcol8 >> 1) ^ fswz(brow)) << 4)
                    + ((bcol8 & 1) << 3);

  // --- MFMA fragment LDS read offsets (same XOR on read) ---
  const int r15 = lane & 15;
  const int kg  = lane >> 4;
  int aoff[4], boff[2];
#pragma unroll
  for (int m = 0; m < 4; ++m) {
    const int r = wm * 64 + m * 16 + r15;      // 0..255
    aoff[m] = r * 64 + ((kg ^ fswz(r)) << 4);
  }
#pragma unroll
  for (int n = 0; n < 2; ++n) {
    const int r = wn * 32 + n * 16 + r15;      // 0..63
    boff[n] = r * 64 + ((kg ^ fswz(r)) << 4);
  }

  i32x4 acc[4][2] = {};
  i32x4 nb;                 // B(t+1) register stage (8 ints), lives over barrier
  i32x4 nb2;

  // ---- prologue ----
  {
    i32x4 b0 = *(const i32x4*)(gB + 0);
    i32x4 b1 = *(const i32x4*)(gB + 4);
    gload16(gA0, &As[0][wid * 1024]);
    gload16(gA1, &As[0][8192 + wid * 1024]);
    VMCNT(2);                       // B(0) arrived; A(0) x2 in flight
    i32x2 pk;
    pk[0] = (b0[0] & 255) | ((b0[1] & 255) << 8) | ((b0[2] & 255) << 16) | (b0[3] << 24);
    pk[1] = (b1[0] & 255) | ((b1[1] & 255) << 8) | ((b1[2] & 255) << 16) | (b1[3] << 24);
    *(i32x2*)(&Bs[0][bldsOff]) = pk;
    {                               // issue B(1)
      const int* g = gB + 64;
      nb  = *(const i32x4*)(g + 0);
      nb2 = *(const i32x4*)(g + 4);
      VMCNT(2);                     // A(0) done; B(1) stays in flight
    }
    LGKM0();
    __builtin_amdgcn_s_barrier();
  }

  for (int t = 0; t < NT; ++t) {
    const int cur = t & 1;
    // 1. issue A(t+1) async -> other buffer
    if (t + 1 < NT) {
      const size_t ko = (size_t)(t + 1) * 64;
      gload16(gA0 + ko, &As[cur ^ 1][wid * 1024]);
      gload16(gA1 + ko, &As[cur ^ 1][8192 + wid * 1024]);
    }
    // 2. compute tile t: 4m x 2n MFMAs (one K=64 step)
    {
      i32x4 av[4], bv[2];
#pragma unroll
      for (int m = 0; m < 4; ++m) av[m] = *(const i32x4*)(&As[cur][aoff[m]]);
#pragma unroll
      for (int n = 0; n < 2; ++n) bv[n] = *(const i32x4*)(&Bs[cur][boff[n]]);
#pragma unroll
      for (int m = 0; m < 4; ++m)
#pragma unroll
        for (int n = 0; n < 2; ++n)
          acc[m][n] = __builtin_amdgcn_mfma_i32_16x16x64_i8(av[m], bv[n], acc[m][n], 0, 0, 0);
    }
    if (t + 1 < NT) {
      // 3. B(t+1) regs ready (A(t+1) still in flight)
      VMCNT(2);
      // 4. pack + swizzled ds_write into Bs[(t+1)&1]
      i32x2 pk;
      pk[0] = (nb[0] & 255) | ((nb[1] & 255) << 8) | ((nb[2] & 255) << 16) | (nb[3] << 24);
      pk[1] = (nb2[0] & 255) | ((nb2[1] & 255) << 8) | ((nb2[2] & 255) << 16) | (nb2[3] << 24);
      *(i32x2*)(&Bs[cur ^ 1][bldsOff]) = pk;
      // 5. issue B(t+2); 6. drain A(t+1), keep B(t+2) in flight
      if (t + 2 < NT) {
        const int* g = gB + (t + 2) * 64;
        nb  = *(const i32x4*)(g + 0);
        nb2 = *(const i32x4*)(g + 4);
        VMCNT(2);
      } else {
        VMCNT(0);                   // full drain only at the last prefetch
      }
      // 7. ds_write visible to all, then barrier
      LGKM0();
      __builtin_amdgcn_s_barrier();
    }
  }

  // --- epilogue: C/D layout col = lane&15, row = (lane>>4)*4 + reg ---
  const float* sN = scaleN + (size_t)e * N + (size_t)bn * 64;
  const float* sM = scaleM + e * TPE;
  float* Cbase = C + (size_t)e * TPE * N + (size_t)bn * 64;
#pragma unroll
  for (int m = 0; m < 4; ++m) {
#pragma unroll
    for (int j = 0; j < 4; ++j) {
      const int row = wm * 64 + m * 16 + kg * 4 + j;   // token row 0..255
      const float smv = sM[row];
      float* cr = Cbase + (size_t)row * N;
#pragma unroll
      for (int n = 0; n < 2; ++n) {
        const int col = wn * 32 + n * 16 + r15;
        cr[col] = ((float)acc[m][n][j] * sN[col]) * smv;  // ref mult order
      }
    }
  }
}

// ---------------------------------------------------------------------------
extern "C" void kernel_launch(void* const* d_in, const int* in_sizes, int n_in,
                              void* d_out, int out_size, void* d_ws, size_t ws_size,
                              hipStream_t stream) {
  const float* x         = (const float*)d_in[0];
  const int*   w13       = (const int*)d_in[1];   // int8 values, int32 storage
  const int*   w2        = (const int*)d_in[2];   // int8 values, int32 storage
  const float* w13_scale = (const float*)d_in[3];
  const float* smooth    = (const float*)d_in[4];
  const float* w2_scale  = (const float*)d_in[5];
  // d_in[6] expert_tokens: unused (uniform TPE per expert by construction)

  uint8_t* ws = (uint8_t*)d_ws;
  int8_t* xq = (int8_t*)ws;                        // 16,777,216 B
  int8_t* hq = (int8_t*)ws;                        // overlay: xq dead after gemm1
  float*  s1 = (float*)(ws + 16777216);            // 16,384 B
  float*  s2 = (float*)(ws + 16777216 + 16384);    // 16,384 B
  float*  y  = (float*)(ws + 16777216 + 32768);    // 46,137,344 B  (total ~63 MB)

  float* out = (float*)d_out;

  quant_x_kernel<<<dim3(T_TOK), dim3(256), 0, stream>>>(x, xq, s1);

  // GEMM1: A=xq (4096,4096), B=w13 (16,2816,4096) -> y (4096,2816)
  gemm_i8_w32_kernel<2 * I_DIM, H_DIM, 44>
      <<<dim3(8 * 2 * 44), dim3(512), 0, stream>>>(
          xq, w13, y, w13_scale, s1);

  act_quant_kernel<<<dim3(T_TOK), dim3(256), 0, stream>>>(y, smooth, hq, s2);

  // GEMM2: A=hq (4096,1408), B=w2 (16,4096,1408) -> out (4096,4096)
  gemm_i8_w32_kernel<H_DIM, I_DIM, 64>
      <<<dim3(8 * 2 * 64), dim3(512), 0, stream>>>(
          hq, w2, out, w2_scale, s2);
}

// Round 14
// 275.527 us; speedup vs baseline: 1.1826x; 1.1826x over previous
//
#include <hip/hip_runtime.h>
#include <stdint.h>

// Problem constants
#define T_TOK 4096
#define H_DIM 4096
#define I_DIM 1408
#define E_NUM 16
#define TPE   256

typedef __attribute__((ext_vector_type(4))) int   i32x4;
typedef __attribute__((ext_vector_type(4))) float f32x4;

// counted waits (T4): vmcnt never drains to 0 in the steady-state loop.
#define VMCNT(n) asm volatile("s_waitcnt vmcnt(" #n ")" ::: "memory")
#define LGKM0()  asm volatile("s_waitcnt lgkmcnt(0)" ::: "memory")

// async global->LDS, 16B/lane. LDS dest is WAVE-UNIFORM base; HW writes
// base + lane*16. Global src is per-lane (so we pre-swizzle the source).
__device__ __forceinline__ void gload16(const void* g, void* l) {
  __builtin_amdgcn_global_load_lds(
      (const __attribute__((address_space(1))) void*)g,
      (__attribute__((address_space(3))) void*)l, 16, 0, 0);
}

// ---------------------------------------------------------------------------
// Kernel 1: dynamic per-token quant of x (f32 -> int8 + scale). 1 block/token.
// ---------------------------------------------------------------------------
__global__ __launch_bounds__(256)
void quant_x_kernel(const float* __restrict__ x,
                    int8_t* __restrict__ xq,
                    float* __restrict__ s1) {
  const int t   = blockIdx.x;
  const int tid = threadIdx.x;
  const float* row = x + (size_t)t * H_DIM;

  f32x4 v[4];
  float mx = 0.0f;
#pragma unroll
  for (int i = 0; i < 4; ++i) {
    v[i] = *(const f32x4*)(row + (size_t)(i * 256 + tid) * 4);
#pragma unroll
    for (int j = 0; j < 4; ++j) mx = fmaxf(mx, fabsf(v[i][j]));
  }
#pragma unroll
  for (int off = 32; off > 0; off >>= 1) mx = fmaxf(mx, __shfl_xor(mx, off));
  __shared__ float wmax[4];
  if ((tid & 63) == 0) wmax[tid >> 6] = mx;
  __syncthreads();
  float s = fmaxf(fmaxf(wmax[0], wmax[1]), fmaxf(wmax[2], wmax[3])) / 127.0f;
  s = fmaxf(s, 1e-30f);

  int* orow = (int*)(xq + (size_t)t * H_DIM);
#pragma unroll
  for (int i = 0; i < 4; ++i) {
    int packed = 0;
#pragma unroll
    for (int j = 0; j < 4; ++j) {
      float q = rintf(v[i][j] / s);              // rintf = half-even = jnp.round
      q = fminf(fmaxf(q, -128.0f), 127.0f);
      packed |= ((int)q & 0xff) << (8 * j);
    }
    orow[i * 256 + tid] = packed;
  }
  if (tid == 0) s1[t] = s;
}

// ---------------------------------------------------------------------------
// Kernel 3: per-token max over h (precomputed by gemm1 epilogue), quantize,
// pack to hq. 1 block/token. Reads 23 MB instead of R11's 46 MB.
// ---------------------------------------------------------------------------
__global__ __launch_bounds__(256)
void act_quant_h_kernel(const float* __restrict__ h,
                        int8_t* __restrict__ hq,
                        float* __restrict__ s2) {
  const int t   = blockIdx.x;
  const int tid = threadIdx.x;
  constexpr int NV = I_DIM / 4;          // 352 vec4 per row
  const float* hrow = h + (size_t)t * I_DIM;

  f32x4 hv[2];
  float mx = 0.0f;
#pragma unroll
  for (int i = 0; i < 2; ++i) {
    const int idx = tid + i * 256;
    hv[i] = (f32x4)(0.0f);
    if (idx < NV) {
      hv[i] = *(const f32x4*)(hrow + idx * 4);
#pragma unroll
      for (int j = 0; j < 4; ++j) mx = fmaxf(mx, fabsf(hv[i][j]));
    }
  }
#pragma unroll
  for (int off = 32; off > 0; off >>= 1) mx = fmaxf(mx, __shfl_xor(mx, off));
  __shared__ float wmax[4];
  if ((tid & 63) == 0) wmax[tid >> 6] = mx;
  __syncthreads();
  float s = fmaxf(fmaxf(wmax[0], wmax[1]), fmaxf(wmax[2], wmax[3])) / 127.0f;
  s = fmaxf(s, 1e-30f);

  int* orow = (int*)(hq + (size_t)t * I_DIM);   // 1408 % 16 == 0, aligned
#pragma unroll
  for (int i = 0; i < 2; ++i) {
    const int idx = tid + i * 256;
    if (idx < NV) {
      int packed = 0;
#pragma unroll
      for (int j = 0; j < 4; ++j) {
        float q = rintf(hv[i][j] / s);
        q = fminf(fmaxf(q, -128.0f), 127.0f);
        packed |= ((int)q & 0xff) << (8 * j);
      }
      orow[idx] = packed;
    }
  }
  if (tid == 0) s2[t] = s;
}

// ---------------------------------------------------------------------------
// GEMM1 fused-lite: R11's exact K-loop/schedule; PAIRED gate/up tiles; the
// epilogue computes h = silu(gate)*up*smooth wave-locally and writes h (f32,
// 23 MB) instead of y (46 MB). NO atomics (R12's regression suspect).
//   Block: M=256 (whole expert) x pair-tile {32 gate cols, 32 up cols}, BK=128.
//   8 waves (4M x 2N); wave n-frag 0 = gate cols, frag 1 = up cols (same col
//   indices) -> silu combine is wave-local; acc count unchanged vs R11.
// Counted-vmcnt schedule (one s_barrier/iter; vmcnt floor 4; A drained
// pre-barrier because global_load_lds tiles are consumed cross-wave).
// XCD-pinned: rid&7 = XCD owns 2 experts. Swizzle: blk ^= (row&7), both sides.
// ---------------------------------------------------------------------------
__global__ __launch_bounds__(512, 4)
void gemm1_fused_kernel(const int8_t* __restrict__ A,
                        const int* __restrict__ B32,
                        float* __restrict__ Hout,
                        const float* __restrict__ w13_scale,
                        const float* __restrict__ smooth,
                        const float* __restrict__ s1) {
  constexpr int K  = H_DIM;            // 4096
  constexpr int NT = K / 128;          // 32
  constexpr int NPAIR = I_DIM / 32;    // 44 pair-tiles
  __shared__ __align__(16) int8_t As[2][256 * 128];    // 32 KB each
  __shared__ __align__(16) int8_t Bs[2][2 * 32 * 128]; //  8 KB each (gate|up)

  const int rid  = blockIdx.x;
  const int xcd  = rid & 7;
  const int slot = rid >> 3;                 // 0 .. 2*NPAIR-1
  const int el   = (slot >= NPAIR) ? 1 : 0;
  const int e    = 2 * xcd + el;
  const int bn   = slot - el * NPAIR;        // 0..43

  const int tid  = threadIdx.x;
  const int lane = tid & 63;
  const int wid  = tid >> 6;          // 0..7
  const int wm   = wid >> 1;          // 0..3  (64-row quadrant of 256)
  const int wn   = wid & 1;           // 0..1  (16-col half of the 32)

  const int8_t* Abase = A + (size_t)e * TPE * K;
  const int* Bgate = B32 + ((size_t)e * (2 * I_DIM) + (size_t)bn * 32) * (size_t)K;
  const int* Bup   = Bgate + (size_t)I_DIM * K;

  // --- A staging: 4 chunks/thread (identical to R11) ---
  const int arow = tid >> 3;
  const int ablk = tid & 7;
  const int agblk = ablk ^ (arow & 7);
  const int8_t* gA[4];
#pragma unroll
  for (int i = 0; i < 4; ++i)
    gA[i] = Abase + (size_t)(arow + 64 * i) * K + (agblk << 4);

  // --- B staging: 1 chunk/thread; tile=tid>>8 (0 gate, 1 up), 32 rows x 8 blks
  const int btile = tid >> 8;
  const int bsub  = tid & 255;
  const int brow  = bsub >> 3;                 // 0..31
  const int bblk  = bsub & 7;
  const int* gB = (btile ? Bup : Bgate) + (size_t)brow * K + (bblk << 4);
  const int bldsOff = btile * 4096 + brow * 128 + ((bblk ^ (brow & 7)) << 4);

  // --- MFMA fragment LDS read offsets ---
  const int r15 = lane & 15;
  const int kg  = lane >> 4;
  int aoff[2][4], boff[2][2];
#pragma unroll
  for (int ks = 0; ks < 2; ++ks) {
#pragma unroll
    for (int m = 0; m < 4; ++m) {
      const int r = wm * 64 + m * 16 + r15;
      aoff[ks][m] = r * 128 + (((ks * 4 + kg) ^ (r & 7)) << 4);
    }
#pragma unroll
    for (int n = 0; n < 2; ++n) {               // n = tile (0 gate, 1 up)
      const int r = wn * 16 + r15;              // 0..31
      boff[ks][n] = n * 4096 + r * 128 + (((ks * 4 + kg) ^ (r & 7)) << 4);
    }
  }

  i32x4 acc[4][2] = {};
  i32x4 n0, n1, n2, n3;

  // ---- prologue ----
  {
    i32x4 b0 = *(const i32x4*)(gB + 0);
    i32x4 b1 = *(const i32x4*)(gB + 4);
    i32x4 b2 = *(const i32x4*)(gB + 8);
    i32x4 b3 = *(const i32x4*)(gB + 12);
#pragma unroll
    for (int i = 0; i < 4; ++i)
      gload16(gA[i], &As[0][i * 8192 + wid * 1024]);
    VMCNT(4);
    i32x4 pk;
    pk[0] = (b0[0] & 255) | ((b0[1] & 255) << 8) | ((b0[2] & 255) << 16) | (b0[3] << 24);
    pk[1] = (b1[0] & 255) | ((b1[1] & 255) << 8) | ((b1[2] & 255) << 16) | (b1[3] << 24);
    pk[2] = (b2[0] & 255) | ((b2[1] & 255) << 8) | ((b2[2] & 255) << 16) | (b2[3] << 24);
    pk[3] = (b3[0] & 255) | ((b3[1] & 255) << 8) | ((b3[2] & 255) << 16) | (b3[3] << 24);
    *(i32x4*)(&Bs[0][bldsOff]) = pk;
    {
      const int* g = gB + 128;
      n0 = *(const i32x4*)(g + 0);
      n1 = *(const i32x4*)(g + 4);
      n2 = *(const i32x4*)(g + 8);
      n3 = *(const i32x4*)(g + 12);
      VMCNT(4);
    }
    LGKM0();
    __builtin_amdgcn_s_barrier();
  }

  for (int t = 0; t < NT; ++t) {
    const int cur = t & 1;
    if (t + 1 < NT) {
      const size_t ko = (size_t)(t + 1) * 128;
#pragma unroll
      for (int i = 0; i < 4; ++i)
        gload16(gA[i] + ko, &As[cur ^ 1][i * 8192 + wid * 1024]);
    }
#pragma unroll
    for (int ks = 0; ks < 2; ++ks) {
      i32x4 av[4], bv[2];
#pragma unroll
      for (int m = 0; m < 4; ++m) av[m] = *(const i32x4*)(&As[cur][aoff[ks][m]]);
#pragma unroll
      for (int n = 0; n < 2; ++n) bv[n] = *(const i32x4*)(&Bs[cur][boff[ks][n]]);
#pragma unroll
      for (int m = 0; m < 4; ++m)
#pragma unroll
        for (int n = 0; n < 2; ++n)
          acc[m][n] = __builtin_amdgcn_mfma_i32_16x16x64_i8(av[m], bv[n], acc[m][n], 0, 0, 0);
    }
    if (t + 1 < NT) {
      VMCNT(4);
      i32x4 pk;
      pk[0] = (n0[0] & 255) | ((n0[1] & 255) << 8) | ((n0[2] & 255) << 16) | (n0[3] << 24);
      pk[1] = (n1[0] & 255) | ((n1[1] & 255) << 8) | ((n1[2] & 255) << 16) | (n1[3] << 24);
      pk[2] = (n2[0] & 255) | ((n2[1] & 255) << 8) | ((n2[2] & 255) << 16) | (n2[3] << 24);
      pk[3] = (n3[0] & 255) | ((n3[1] & 255) << 8) | ((n3[2] & 255) << 16) | (n3[3] << 24);
      *(i32x4*)(&Bs[cur ^ 1][bldsOff]) = pk;
      if (t + 2 < NT) {
        const int* g = gB + (t + 2) * 128;
        n0 = *(const i32x4*)(g + 0);
        n1 = *(const i32x4*)(g + 4);
        n2 = *(const i32x4*)(g + 8);
        n3 = *(const i32x4*)(g + 12);
        VMCNT(4);
      } else {
        VMCNT(0);
      }
      LGKM0();
      __builtin_amdgcn_s_barrier();
    }
  }

  // --- fused epilogue (NO atomics): h = silu(gate)*up*smooth, write h ---
  // C/D layout: col = lane&15 (r15), row = kg*4 + reg j.
  const int col = bn * 32 + wn * 16 + r15;            // 0..1407 (i-index)
  const float sNg = w13_scale[(size_t)e * (2 * I_DIM) + col];
  const float sNu = w13_scale[(size_t)e * (2 * I_DIM) + I_DIM + col];
  const float smo = smooth[(size_t)e * I_DIM + col];
  const float* s1p = s1 + e * TPE;
  float* hbase = Hout + (size_t)e * TPE * I_DIM + col;
#pragma unroll
  for (int m = 0; m < 4; ++m) {
#pragma unroll
    for (int j = 0; j < 4; ++j) {
      const int row = wm * 64 + m * 16 + kg * 4 + j;
      const float s1r = s1p[row];
      const float g = ((float)acc[m][0][j] * sNg) * s1r;   // ref mult order
      const float u = ((float)acc[m][1][j] * sNu) * s1r;
      const float sig = 1.0f / (1.0f + expf(-g));
      hbase[(size_t)row * I_DIM] = ((g * sig) * u) * smo;
    }
  }
}

// ---------------------------------------------------------------------------
// GEMM2 (unchanged from R11): A=hq, B32=w2, out = ((f32)acc*sN)*sM.
// ---------------------------------------------------------------------------
template <int N, int K, int NBLK>   // NBLK = N/64
__global__ __launch_bounds__(512, 4)
void gemm_i8_w32_kernel(const int8_t* __restrict__ A,
                        const int* __restrict__ B32,
                        float* __restrict__ C,
                        const float* __restrict__ scaleN,
                        const float* __restrict__ scaleM) {
  constexpr int NT = K / 128;
  __shared__ __align__(16) int8_t As[2][256 * 128];  // 32 KB each
  __shared__ __align__(16) int8_t Bs[2][64 * 128];   //  8 KB each

  const int rid  = blockIdx.x;
  const int xcd  = rid & 7;
  const int slot = rid >> 3;
  const int el   = (slot >= NBLK) ? 1 : 0;
  const int e    = 2 * xcd + el;
  const int bn   = slot - el * NBLK;

  const int tid  = threadIdx.x;
  const int lane = tid & 63;
  const int wid  = tid >> 6;
  const int wm   = wid >> 1;
  const int wn   = wid & 1;

  const int8_t* Abase = A + (size_t)e * TPE * K;
  const int*    Bbase = B32 + ((size_t)e * N + (size_t)bn * 64) * (size_t)K;

  const int arow = tid >> 3;
  const int ablk = tid & 7;
  const int agblk = ablk ^ (arow & 7);
  const int8_t* gA[4];
#pragma unroll
  for (int i = 0; i < 4; ++i)
    gA[i] = Abase + (size_t)(arow + 64 * i) * K + (agblk << 4);

  const int brow = tid >> 3;
  const int bblk = tid & 7;
  const int* gB = Bbase + (size_t)brow * K + (bblk << 4);
  const int bldsOff = brow * 128 + ((bblk ^ (brow & 7)) << 4);

  const int r15 = lane & 15;
  const int kg  = lane >> 4;
  int aoff[2][4], boff[2][2];
#pragma unroll
  for (int ks = 0; ks < 2; ++ks) {
#pragma unroll
    for (int m = 0; m < 4; ++m) {
      const int r = wm * 64 + m * 16 + r15;
      aoff[ks][m] = r * 128 + (((ks * 4 + kg) ^ (r & 7)) << 4);
    }
#pragma unroll
    for (int n = 0; n < 2; ++n) {
      const int r = wn * 32 + n * 16 + r15;
      boff[ks][n] = r * 128 + (((ks * 4 + kg) ^ (r & 7)) << 4);
    }
  }

  i32x4 acc[4][2] = {};
  i32x4 n0, n1, n2, n3;

  {
    i32x4 b0 = *(const i32x4*)(gB + 0);
    i32x4 b1 = *(const i32x4*)(gB + 4);
    i32x4 b2 = *(const i32x4*)(gB + 8);
    i32x4 b3 = *(const i32x4*)(gB + 12);
#pragma unroll
    for (int i = 0; i < 4; ++i)
      gload16(gA[i], &As[0][i * 8192 + wid * 1024]);
    VMCNT(4);
    i32x4 pk;
    pk[0] = (b0[0] & 255) | ((b0[1] & 255) << 8) | ((b0[2] & 255) << 16) | (b0[3] << 24);
    pk[1] = (b1[0] & 255) | ((b1[1] & 255) << 8) | ((b1[2] & 255) << 16) | (b1[3] << 24);
    pk[2] = (b2[0] & 255) | ((b2[1] & 255) << 8) | ((b2[2] & 255) << 16) | (b2[3] << 24);
    pk[3] = (b3[0] & 255) | ((b3[1] & 255) << 8) | ((b3[2] & 255) << 16) | (b3[3] << 24);
    *(i32x4*)(&Bs[0][bldsOff]) = pk;
    if (NT > 1) {
      const int* g = gB + 128;
      n0 = *(const i32x4*)(g + 0);
      n1 = *(const i32x4*)(g + 4);
      n2 = *(const i32x4*)(g + 8);
      n3 = *(const i32x4*)(g + 12);
      VMCNT(4);
    } else {
      VMCNT(0);
    }
    LGKM0();
    __builtin_amdgcn_s_barrier();
  }

  for (int t = 0; t < NT; ++t) {
    const int cur = t & 1;
    if (t + 1 < NT) {
      const size_t ko = (size_t)(t + 1) * 128;
#pragma unroll
      for (int i = 0; i < 4; ++i)
        gload16(gA[i] + ko, &As[cur ^ 1][i * 8192 + wid * 1024]);
    }
#pragma unroll
    for (int ks = 0; ks < 2; ++ks) {
      i32x4 av[4], bv[2];
#pragma unroll
      for (int m = 0; m < 4; ++m) av[m] = *(const i32x4*)(&As[cur][aoff[ks][m]]);
#pragma unroll
      for (int n = 0; n < 2; ++n) bv[n] = *(const i32x4*)(&Bs[cur][boff[ks][n]]);
#pragma unroll
      for (int m = 0; m < 4; ++m)
#pragma unroll
        for (int n = 0; n < 2; ++n)
          acc[m][n] = __builtin_amdgcn_mfma_i32_16x16x64_i8(av[m], bv[n], acc[m][n], 0, 0, 0);
    }
    if (t + 1 < NT) {
      VMCNT(4);
      i32x4 pk;
      pk[0] = (n0[0] & 255) | ((n0[1] & 255) << 8) | ((n0[2] & 255) << 16) | (n0[3] << 24);
      pk[1] = (n1[0] & 255) | ((n1[1] & 255) << 8) | ((n1[2] & 255) << 16) | (n1[3] << 24);
      pk[2] = (n2[0] & 255) | ((n2[1] & 255) << 8) | ((n2[2] & 255) << 16) | (n2[3] << 24);
      pk[3] = (n3[0] & 255) | ((n3[1] & 255) << 8) | ((n3[2] & 255) << 16) | (n3[3] << 24);
      *(i32x4*)(&Bs[cur ^ 1][bldsOff]) = pk;
      if (t + 2 < NT) {
        const int* g = gB + (t + 2) * 128;
        n0 = *(const i32x4*)(g + 0);
        n1 = *(const i32x4*)(g + 4);
        n2 = *(const i32x4*)(g + 8);
        n3 = *(const i32x4*)(g + 12);
        VMCNT(4);
      } else {
        VMCNT(0);
      }
      LGKM0();
      __builtin_amdgcn_s_barrier();
    }
  }

  const float* sN = scaleN + (size_t)e * N + (size_t)bn * 64;
  const float* sM = scaleM + e * TPE;
  float* Cbase = C + (size_t)e * TPE * N + (size_t)bn * 64;
#pragma unroll
  for (int m = 0; m < 4; ++m) {
#pragma unroll
    for (int j = 0; j < 4; ++j) {
      const int row = wm * 64 + m * 16 + kg * 4 + j;
      const float smv = sM[row];
      float* cr = Cbase + (size_t)row * N;
#pragma unroll
      for (int n = 0; n < 2; ++n) {
        const int col = wn * 32 + n * 16 + r15;
        cr[col] = ((float)acc[m][n][j] * sN[col]) * smv;
      }
    }
  }
}

// ---------------------------------------------------------------------------
extern "C" void kernel_launch(void* const* d_in, const int* in_sizes, int n_in,
                              void* d_out, int out_size, void* d_ws, size_t ws_size,
                              hipStream_t stream) {
  const float* x         = (const float*)d_in[0];
  const int*   w13       = (const int*)d_in[1];   // int8 values, int32 storage
  const int*   w2        = (const int*)d_in[2];   // int8 values, int32 storage
  const float* w13_scale = (const float*)d_in[3];
  const float* smooth    = (const float*)d_in[4];
  const float* w2_scale  = (const float*)d_in[5];
  // d_in[6] expert_tokens: unused (uniform TPE per expert by construction)

  uint8_t* ws = (uint8_t*)d_ws;
  int8_t* xq = (int8_t*)ws;                        // 16,777,216 B
  int8_t* hq = (int8_t*)ws;                        // overlay: xq dead after gemm1
  float*  s1 = (float*)(ws + 16777216);            // 16,384 B
  float*  s2 = (float*)(ws + 16777216 + 16384);    // 16,384 B
  float*  h  = (float*)(ws + 16777216 + 32768);    // 23,068,672 B (~40 MB total)

  float* out = (float*)d_out;

  quant_x_kernel<<<dim3(T_TOK), dim3(256), 0, stream>>>(x, xq, s1);

  // GEMM1 fused-lite: xq x w13 -> h = silu(gate)*up*smooth (23 MB, no y)
  gemm1_fused_kernel<<<dim3(8 * 2 * (I_DIM / 32)), dim3(512), 0, stream>>>(
      xq, w13, h, w13_scale, smooth, s1);

  act_quant_h_kernel<<<dim3(T_TOK), dim3(256), 0, stream>>>(h, hq, s2);

  // GEMM2: A=hq (4096,1408), B=w2 (16,4096,1408) -> out (4096,4096)
  gemm_i8_w32_kernel<H_DIM, I_DIM, 64>
      <<<dim3(8 * 2 * 64), dim3(512), 0, stream>>>(
          hq, w2, out, w2_scale, s2);
}